// Round 2
// baseline (324.485 us; speedup 1.0000x reference)
//
#include <hip/hip_runtime.h>
#include <hip/hip_bf16.h>

#define D_DIM 1024
#define F_DIM 1024
#define NTOK  4096
#define NEXP  8
#define CAP   4096

typedef __attribute__((ext_vector_type(8))) short bf16x8;
typedef __attribute__((ext_vector_type(4))) float f32x4;
typedef __attribute__((ext_vector_type(8))) unsigned short u16x8;

__device__ __forceinline__ unsigned short f2bf(float f) {
    unsigned int u = __float_as_uint(f);
    u = u + 0x7fffu + ((u >> 16) & 1u);
    return (unsigned short)(u >> 16);
}

__device__ __forceinline__ void async_copy16(void* lds, const void* gsrc) {
    __builtin_amdgcn_global_load_lds(
        (const __attribute__((address_space(1))) unsigned int*)gsrc,
        (__attribute__((address_space(3))) unsigned int*)lds, 16, 0, 0);
}

// ---------------- f32 -> bf16 conversion (8 elems/thread) ----------------
__global__ __launch_bounds__(256) void cvt_kernel(const float* __restrict__ in,
                                                  unsigned short* __restrict__ out, int n) {
    int i = (blockIdx.x * 256 + threadIdx.x) * 8;
    if (i >= n) return;
    const float4* p = (const float4*)(in + i);
    float4 a = p[0], b = p[1];
    u16x8 r;
    r[0] = f2bf(a.x); r[1] = f2bf(a.y); r[2] = f2bf(a.z); r[3] = f2bf(a.w);
    r[4] = f2bf(b.x); r[5] = f2bf(b.y); r[6] = f2bf(b.z); r[7] = f2bf(b.w);
    *(u16x8*)(out + i) = r;
}

// ---------------- router: logits, top-2, softmax, expert lists ----------------
__global__ __launch_bounds__(256) void router_kernel(
    const float* __restrict__ x, const float* __restrict__ rw, const float* __restrict__ bias,
    int* counts, int* list, float* wlist)
{
    const int wave = threadIdx.x >> 6, lane = threadIdx.x & 63;
    const int t = blockIdx.x * 4 + wave;
    double s[NEXP];
    #pragma unroll
    for (int e = 0; e < NEXP; ++e) s[e] = 0.0;
    const float* xp = x + (size_t)t * D_DIM;
    for (int kk = 0; kk < D_DIM; kk += 64) {
        float xv = xp[kk + lane];
        #pragma unroll
        for (int e = 0; e < NEXP; ++e)
            s[e] += (double)xv * (double)rw[e * D_DIM + kk + lane];
    }
    #pragma unroll
    for (int e = 0; e < NEXP; ++e) {
        double v = s[e];
        for (int off = 32; off; off >>= 1) v += __shfl_xor(v, off, 64);
        s[e] = v;
    }
    if (lane == 0) {
        float logit[NEXP], b2[NEXP];
        #pragma unroll
        for (int e = 0; e < NEXP; ++e) { logit[e] = (float)s[e]; b2[e] = logit[e] + bias[e]; }
        int i0 = 0;
        #pragma unroll
        for (int e = 1; e < NEXP; ++e) if (b2[e] > b2[i0]) i0 = e;
        int i1 = -1;
        #pragma unroll
        for (int e = 0; e < NEXP; ++e)
            if (e != i0 && (i1 < 0 || b2[e] > b2[i1])) i1 = e;
        float m = fmaxf(logit[i0], logit[i1]);
        float e0 = expf(logit[i0] - m), e1 = expf(logit[i1] - m);
        float inv = 1.0f / (e0 + e1);
        int p0 = atomicAdd(&counts[i0], 1);
        list[i0 * CAP + p0] = t; wlist[i0 * CAP + p0] = e0 * inv;
        int p1 = atomicAdd(&counts[i1], 1);
        list[i1 * CAP + p1] = t; wlist[i1 * CAP + p1] = e1 * inv;
    }
}

__global__ void scan_kernel(const int* __restrict__ counts, int* __restrict__ offs) {
    if (threadIdx.x == 0) {
        int a = 0;
        for (int e = 0; e < NEXP; ++e) { offs[e] = a; a += counts[e]; }
        offs[NEXP] = a;
    }
}

// ---------------- grouped GEMM1: H = gelu(Xg @ W1_e^T), bf16 out ----------------
__global__ __launch_bounds__(256) void gemm1_kernel(
    const unsigned short* __restrict__ xb,
    const unsigned short* __restrict__ w1b,
    const int* __restrict__ counts, const int* __restrict__ offs,
    const int* __restrict__ list,
    unsigned short* __restrict__ H)
{
    const int e  = blockIdx.y >> 5;
    const int rb = blockIdx.y & 31;
    const int ne = counts[e];
    if (rb * 128 >= ne) return;
    const int row0 = rb * 128;
    const int n0 = blockIdx.x * 128;
    const int hbase = offs[e];

    __shared__ __align__(16) unsigned short As[128 * 32];
    __shared__ __align__(16) unsigned short Bs[128 * 32];
    __shared__ int toks[128];

    const int tid = threadIdx.x;
    if (tid < 128) {
        int i = row0 + tid;
        if (i >= ne) i = ne - 1;
        toks[tid] = list[e * CAP + i];
    }
    __syncthreads();

    const int wave = tid >> 6, lane = tid & 63;
    const int wr = wave >> 1, wc = wave & 1;

    const int c0 = wave, c1 = wave + 4;      // two 16-row LDS chunks per wave
    const int lrow = lane >> 2;
    const int lcol = (lane & 3) * 8;
    const int ar0 = c0 * 16 + lrow;
    const int ar1 = c1 * 16 + lrow;
    const unsigned short* a0 = xb + (size_t)toks[ar0] * D_DIM + lcol;
    const unsigned short* a1 = xb + (size_t)toks[ar1] * D_DIM + lcol;
    const unsigned short* bp = w1b + (size_t)e * F_DIM * D_DIM;
    const unsigned short* b0 = bp + (size_t)(n0 + ar0) * D_DIM + lcol;
    const unsigned short* b1 = bp + (size_t)(n0 + ar1) * D_DIM + lcol;

    unsigned short* Ad0 = &As[c0 * 512];
    unsigned short* Ad1 = &As[c1 * 512];
    unsigned short* Bd0 = &Bs[c0 * 512];
    unsigned short* Bd1 = &Bs[c1 * 512];

    f32x4 acc[4][4];
    #pragma unroll
    for (int m = 0; m < 4; ++m)
        #pragma unroll
        for (int n = 0; n < 4; ++n) acc[m][n] = (f32x4){0.f, 0.f, 0.f, 0.f};

    const int arow = lane & 15;
    const int kg = (lane >> 4) * 8;

    for (int k0 = 0; k0 < D_DIM; k0 += 32) {
        async_copy16(Ad0, a0 + k0);
        async_copy16(Ad1, a1 + k0);
        async_copy16(Bd0, b0 + k0);
        async_copy16(Bd1, b1 + k0);
        __syncthreads();
        bf16x8 af[4], bfr[4];
        #pragma unroll
        for (int m = 0; m < 4; ++m)
            af[m] = *(const bf16x8*)&As[(wr * 64 + m * 16 + arow) * 32 + kg];
        #pragma unroll
        for (int n = 0; n < 4; ++n)
            bfr[n] = *(const bf16x8*)&Bs[(wc * 64 + n * 16 + arow) * 32 + kg];
        #pragma unroll
        for (int m = 0; m < 4; ++m)
            #pragma unroll
            for (int n = 0; n < 4; ++n)
                acc[m][n] = __builtin_amdgcn_mfma_f32_16x16x32_bf16(af[m], bfr[n], acc[m][n], 0, 0, 0);
        __syncthreads();
    }

    #pragma unroll
    for (int m = 0; m < 4; ++m) {
        #pragma unroll
        for (int j = 0; j < 4; ++j) {
            int ri = wr * 64 + m * 16 + (lane >> 4) * 4 + j;
            int i = row0 + ri;
            if (i < ne) {
                unsigned short* hp = H + (size_t)(hbase + i) * F_DIM + n0 + wc * 64;
                #pragma unroll
                for (int n = 0; n < 4; ++n) {
                    float v = acc[m][n][j];
                    float g = 0.5f * v * (1.0f + erff(v * 0.70710678118654752f));
                    hp[n * 16 + (lane & 15)] = f2bf(g);
                }
            }
        }
    }
}

// ---------------- grouped GEMM2: out += w * (H @ W2_e^T), atomic f32 ----------------
__global__ __launch_bounds__(256) void gemm2_kernel(
    const unsigned short* __restrict__ H,
    const unsigned short* __restrict__ w2b,
    const int* __restrict__ counts, const int* __restrict__ offs,
    const int* __restrict__ list, const float* __restrict__ wlist,
    float* __restrict__ out)
{
    const int e  = blockIdx.y >> 5;
    const int rb = blockIdx.y & 31;
    const int ne = counts[e];
    if (rb * 128 >= ne) return;
    const int row0 = rb * 128;
    const int n0 = blockIdx.x * 128;
    const int hbase = offs[e];

    __shared__ __align__(16) unsigned short As[128 * 32];
    __shared__ __align__(16) unsigned short Bs[128 * 32];
    __shared__ int toks[128];
    __shared__ float wts[128];

    const int tid = threadIdx.x;
    if (tid < 128) {
        int i = row0 + tid;
        if (i >= ne) i = ne - 1;
        toks[tid] = list[e * CAP + i];
        wts[tid]  = wlist[e * CAP + i];
    }
    __syncthreads();

    const int wave = tid >> 6, lane = tid & 63;
    const int wr = wave >> 1, wc = wave & 1;

    const int c0 = wave, c1 = wave + 4;
    const int lrow = lane >> 2;
    const int lcol = (lane & 3) * 8;
    const int ar0 = c0 * 16 + lrow;
    const int ar1 = c1 * 16 + lrow;
    const unsigned short* a0 = H + (size_t)(hbase + row0 + ar0) * F_DIM + lcol;
    const unsigned short* a1 = H + (size_t)(hbase + row0 + ar1) * F_DIM + lcol;
    const unsigned short* bp = w2b + (size_t)e * D_DIM * F_DIM;
    const unsigned short* b0 = bp + (size_t)(n0 + ar0) * F_DIM + lcol;
    const unsigned short* b1 = bp + (size_t)(n0 + ar1) * F_DIM + lcol;

    unsigned short* Ad0 = &As[c0 * 512];
    unsigned short* Ad1 = &As[c1 * 512];
    unsigned short* Bd0 = &Bs[c0 * 512];
    unsigned short* Bd1 = &Bs[c1 * 512];

    f32x4 acc[4][4];
    #pragma unroll
    for (int m = 0; m < 4; ++m)
        #pragma unroll
        for (int n = 0; n < 4; ++n) acc[m][n] = (f32x4){0.f, 0.f, 0.f, 0.f};

    const int arow = lane & 15;
    const int kg = (lane >> 4) * 8;

    for (int k0 = 0; k0 < F_DIM; k0 += 32) {
        async_copy16(Ad0, a0 + k0);
        async_copy16(Ad1, a1 + k0);
        async_copy16(Bd0, b0 + k0);
        async_copy16(Bd1, b1 + k0);
        __syncthreads();
        bf16x8 af[4], bfr[4];
        #pragma unroll
        for (int m = 0; m < 4; ++m)
            af[m] = *(const bf16x8*)&As[(wr * 64 + m * 16 + arow) * 32 + kg];
        #pragma unroll
        for (int n = 0; n < 4; ++n)
            bfr[n] = *(const bf16x8*)&Bs[(wc * 64 + n * 16 + arow) * 32 + kg];
        #pragma unroll
        for (int m = 0; m < 4; ++m)
            #pragma unroll
            for (int n = 0; n < 4; ++n)
                acc[m][n] = __builtin_amdgcn_mfma_f32_16x16x32_bf16(af[m], bfr[n], acc[m][n], 0, 0, 0);
        __syncthreads();
    }

    #pragma unroll
    for (int m = 0; m < 4; ++m) {
        #pragma unroll
        for (int j = 0; j < 4; ++j) {
            int ri = wr * 64 + m * 16 + (lane >> 4) * 4 + j;
            int i = row0 + ri;
            if (i < ne) {
                int t = toks[ri];
                float wt = wts[ri];
                float* op = out + (size_t)t * D_DIM + n0 + wc * 64;
                #pragma unroll
                for (int n = 0; n < 4; ++n)
                    atomicAdd(&op[n * 16 + (lane & 15)], wt * acc[m][n][j]);
            }
        }
    }
}

extern "C" void kernel_launch(void* const* d_in, const int* in_sizes, int n_in,
                              void* d_out, int out_size, void* d_ws, size_t ws_size,
                              hipStream_t stream)
{
    const float* x    = (const float*)d_in[0];
    const float* bias = (const float*)d_in[1];
    const float* rw   = (const float*)d_in[2];
    const float* w1   = (const float*)d_in[3];
    const float* w2   = (const float*)d_in[4];
    float* out = (float*)d_out;

    char* ws = (char*)d_ws;
    size_t cur = 0;
    auto alloc = [&](size_t bytes) -> void* {
        void* p = (void*)(ws + cur);
        cur += (bytes + 255) & ~(size_t)255;
        return p;
    };
    unsigned short* xb   = (unsigned short*)alloc((size_t)NTOK * D_DIM * 2);
    unsigned short* w1b  = (unsigned short*)alloc((size_t)NEXP * F_DIM * D_DIM * 2);
    unsigned short* w2b  = (unsigned short*)alloc((size_t)NEXP * F_DIM * D_DIM * 2);
    unsigned short* Hb   = (unsigned short*)alloc((size_t)(NTOK * 2 + 128) * F_DIM * 2);
    int*   list   = (int*)alloc(NEXP * CAP * 4);
    float* wlist  = (float*)alloc(NEXP * CAP * 4);
    int*   counts = (int*)alloc(64);
    int*   offs   = (int*)alloc(64);

    hipMemsetAsync(counts, 0, 64, stream);
    hipMemsetAsync(out, 0, (size_t)out_size * 4, stream);

    cvt_kernel<<<NTOK * D_DIM / 2048, 256, 0, stream>>>(x, xb, NTOK * D_DIM);
    cvt_kernel<<<NEXP * F_DIM * D_DIM / 2048, 256, 0, stream>>>(w1, w1b, NEXP * F_DIM * D_DIM);
    cvt_kernel<<<NEXP * F_DIM * D_DIM / 2048, 256, 0, stream>>>(w2, w2b, NEXP * F_DIM * D_DIM);
    router_kernel<<<NTOK / 4, 256, 0, stream>>>(x, rw, bias, counts, list, wlist);
    scan_kernel<<<1, 64, 0, stream>>>(counts, offs);
    gemm1_kernel<<<dim3(8, 256), 256, 0, stream>>>(xb, w1b, counts, offs, list, Hb);
    gemm2_kernel<<<dim3(8, 256), 256, 0, stream>>>(Hb, w2b, counts, offs, list, wlist, out);
}

// Round 3
// 235.176 us; speedup vs baseline: 1.3798x; 1.3798x over previous
//
#include <hip/hip_runtime.h>
#include <hip/hip_bf16.h>

#define D_DIM 1024
#define F_DIM 1024
#define NTOK  4096
#define NEXP  8
#define CAP   4096

typedef __attribute__((ext_vector_type(8))) short bf16x8;
typedef __attribute__((ext_vector_type(4))) float f32x4;
typedef __attribute__((ext_vector_type(8))) unsigned short u16x8;

__device__ __forceinline__ unsigned short f2bf(float f) {
    unsigned int u = __float_as_uint(f);
    u = u + 0x7fffu + ((u >> 16) & 1u);
    return (unsigned short)(u >> 16);
}

__device__ __forceinline__ void async_copy16(void* lds, const void* gsrc) {
    __builtin_amdgcn_global_load_lds(
        (const __attribute__((address_space(1))) unsigned int*)gsrc,
        (__attribute__((address_space(3))) unsigned int*)lds, 16, 0, 0);
}

// ---------------- f32 -> bf16 conversion (8 elems/thread) ----------------
__global__ __launch_bounds__(256) void cvt_kernel(const float* __restrict__ in,
                                                  unsigned short* __restrict__ out, int n) {
    int i = (blockIdx.x * 256 + threadIdx.x) * 8;
    if (i >= n) return;
    const float4* p = (const float4*)(in + i);
    float4 a = p[0], b = p[1];
    u16x8 r;
    r[0] = f2bf(a.x); r[1] = f2bf(a.y); r[2] = f2bf(a.z); r[3] = f2bf(a.w);
    r[4] = f2bf(b.x); r[5] = f2bf(b.y); r[6] = f2bf(b.z); r[7] = f2bf(b.w);
    *(u16x8*)(out + i) = r;
}

// ---------------- router logits: one wave per token, f64 accumulation ----------------
__global__ __launch_bounds__(256) void logits_kernel(
    const float* __restrict__ x, const float* __restrict__ rw,
    float* __restrict__ logits)
{
    const int wave = threadIdx.x >> 6, lane = threadIdx.x & 63;
    const int t = blockIdx.x * 4 + wave;
    double s[NEXP];
    #pragma unroll
    for (int e = 0; e < NEXP; ++e) s[e] = 0.0;
    const float* xp = x + (size_t)t * D_DIM;
    for (int kk = 0; kk < D_DIM; kk += 64) {
        float xv = xp[kk + lane];
        #pragma unroll
        for (int e = 0; e < NEXP; ++e)
            s[e] += (double)xv * (double)rw[e * D_DIM + kk + lane];
    }
    #pragma unroll
    for (int e = 0; e < NEXP; ++e) {
        double v = s[e];
        for (int off = 32; off; off >>= 1) v += __shfl_xor(v, off, 64);
        s[e] = v;
    }
    if (lane == 0) {
        #pragma unroll
        for (int e = 0; e < NEXP; ++e) logits[(size_t)t * NEXP + e] = (float)s[e];
    }
}

// ---------------- assign: top-2 + softmax + LDS-aggregated expert lists ----------------
// Replaces 8192 same-cache-line global atomics (measured 109us serialization)
// with per-block LDS histogram + 8 global atomics per block (16 blocks).
__global__ __launch_bounds__(256) void assign_kernel(
    const float* __restrict__ logits, const float* __restrict__ bias,
    int* counts, int* list, float* wlist)
{
    __shared__ int lcnt[NEXP];
    __shared__ int lbase[NEXP];
    const int tid = threadIdx.x;
    const int t = blockIdx.x * 256 + tid;
    if (tid < NEXP) lcnt[tid] = 0;
    __syncthreads();

    float lg[NEXP], b2[NEXP];
    #pragma unroll
    for (int e = 0; e < NEXP; ++e) {
        lg[e] = logits[(size_t)t * NEXP + e];
        b2[e] = lg[e] + bias[e];
    }
    // top-2 on biased logits, lowest-index tie-break; carry raw logits through
    // the compare chain (no runtime indexing -> stays in registers).
    int i0 = 0; float b0v = b2[0], l0v = lg[0];
    #pragma unroll
    for (int e = 1; e < NEXP; ++e)
        if (b2[e] > b0v) { b0v = b2[e]; l0v = lg[e]; i0 = e; }
    int i1 = -1; float b1v = 0.f, l1v = 0.f;
    #pragma unroll
    for (int e = 0; e < NEXP; ++e) {
        if (e == i0) continue;
        bool take = (i1 < 0) || (b2[e] > b1v);
        if (take) { i1 = e; b1v = b2[e]; l1v = lg[e]; }
    }
    float m = fmaxf(l0v, l1v);
    float e0 = expf(l0v - m), e1 = expf(l1v - m);
    float inv = 1.0f / (e0 + e1);

    int lp0 = atomicAdd(&lcnt[i0], 1);
    int lp1 = atomicAdd(&lcnt[i1], 1);
    __syncthreads();
    if (tid < NEXP) lbase[tid] = atomicAdd(&counts[tid], lcnt[tid]);
    __syncthreads();

    int p0 = lbase[i0] + lp0;
    list[i0 * CAP + p0] = t; wlist[i0 * CAP + p0] = e0 * inv;
    int p1 = lbase[i1] + lp1;
    list[i1 * CAP + p1] = t; wlist[i1 * CAP + p1] = e1 * inv;
}

__global__ void scan_kernel(const int* __restrict__ counts, int* __restrict__ offs) {
    if (threadIdx.x == 0) {
        int a = 0;
        for (int e = 0; e < NEXP; ++e) { offs[e] = a; a += counts[e]; }
        offs[NEXP] = a;
    }
}

// ---------------- grouped GEMM1: H = gelu(Xg @ W1_e^T), bf16 out ----------------
__global__ __launch_bounds__(256) void gemm1_kernel(
    const unsigned short* __restrict__ xb,
    const unsigned short* __restrict__ w1b,
    const int* __restrict__ counts, const int* __restrict__ offs,
    const int* __restrict__ list,
    unsigned short* __restrict__ H)
{
    const int e  = blockIdx.y >> 5;
    const int rb = blockIdx.y & 31;
    const int ne = counts[e];
    if (rb * 128 >= ne) return;
    const int row0 = rb * 128;
    const int n0 = blockIdx.x * 128;
    const int hbase = offs[e];

    __shared__ __align__(16) unsigned short As[128 * 32];
    __shared__ __align__(16) unsigned short Bs[128 * 32];
    __shared__ int toks[128];

    const int tid = threadIdx.x;
    if (tid < 128) {
        int i = row0 + tid;
        if (i >= ne) i = ne - 1;
        toks[tid] = list[e * CAP + i];
    }
    __syncthreads();

    const int wave = tid >> 6, lane = tid & 63;
    const int wr = wave >> 1, wc = wave & 1;

    const int c0 = wave, c1 = wave + 4;      // two 16-row LDS chunks per wave
    const int lrow = lane >> 2;
    const int lcol = (lane & 3) * 8;
    const int ar0 = c0 * 16 + lrow;
    const int ar1 = c1 * 16 + lrow;
    const unsigned short* a0 = xb + (size_t)toks[ar0] * D_DIM + lcol;
    const unsigned short* a1 = xb + (size_t)toks[ar1] * D_DIM + lcol;
    const unsigned short* bp = w1b + (size_t)e * F_DIM * D_DIM;
    const unsigned short* b0 = bp + (size_t)(n0 + ar0) * D_DIM + lcol;
    const unsigned short* b1 = bp + (size_t)(n0 + ar1) * D_DIM + lcol;

    unsigned short* Ad0 = &As[c0 * 512];
    unsigned short* Ad1 = &As[c1 * 512];
    unsigned short* Bd0 = &Bs[c0 * 512];
    unsigned short* Bd1 = &Bs[c1 * 512];

    f32x4 acc[4][4];
    #pragma unroll
    for (int m = 0; m < 4; ++m)
        #pragma unroll
        for (int n = 0; n < 4; ++n) acc[m][n] = (f32x4){0.f, 0.f, 0.f, 0.f};

    const int arow = lane & 15;
    const int kg = (lane >> 4) * 8;

    for (int k0 = 0; k0 < D_DIM; k0 += 32) {
        async_copy16(Ad0, a0 + k0);
        async_copy16(Ad1, a1 + k0);
        async_copy16(Bd0, b0 + k0);
        async_copy16(Bd1, b1 + k0);
        __syncthreads();
        bf16x8 af[4], bfr[4];
        #pragma unroll
        for (int m = 0; m < 4; ++m)
            af[m] = *(const bf16x8*)&As[(wr * 64 + m * 16 + arow) * 32 + kg];
        #pragma unroll
        for (int n = 0; n < 4; ++n)
            bfr[n] = *(const bf16x8*)&Bs[(wc * 64 + n * 16 + arow) * 32 + kg];
        #pragma unroll
        for (int m = 0; m < 4; ++m)
            #pragma unroll
            for (int n = 0; n < 4; ++n)
                acc[m][n] = __builtin_amdgcn_mfma_f32_16x16x32_bf16(af[m], bfr[n], acc[m][n], 0, 0, 0);
        __syncthreads();
    }

    #pragma unroll
    for (int m = 0; m < 4; ++m) {
        #pragma unroll
        for (int j = 0; j < 4; ++j) {
            int ri = wr * 64 + m * 16 + (lane >> 4) * 4 + j;
            int i = row0 + ri;
            if (i < ne) {
                unsigned short* hp = H + (size_t)(hbase + i) * F_DIM + n0 + wc * 64;
                #pragma unroll
                for (int n = 0; n < 4; ++n) {
                    float v = acc[m][n][j];
                    float g = 0.5f * v * (1.0f + erff(v * 0.70710678118654752f));
                    hp[n * 16 + (lane & 15)] = f2bf(g);
                }
            }
        }
    }
}

// ---------------- grouped GEMM2: out += w * (H @ W2_e^T), atomic f32 ----------------
__global__ __launch_bounds__(256) void gemm2_kernel(
    const unsigned short* __restrict__ H,
    const unsigned short* __restrict__ w2b,
    const int* __restrict__ counts, const int* __restrict__ offs,
    const int* __restrict__ list, const float* __restrict__ wlist,
    float* __restrict__ out)
{
    const int e  = blockIdx.y >> 5;
    const int rb = blockIdx.y & 31;
    const int ne = counts[e];
    if (rb * 128 >= ne) return;
    const int row0 = rb * 128;
    const int n0 = blockIdx.x * 128;
    const int hbase = offs[e];

    __shared__ __align__(16) unsigned short As[128 * 32];
    __shared__ __align__(16) unsigned short Bs[128 * 32];
    __shared__ int toks[128];
    __shared__ float wts[128];

    const int tid = threadIdx.x;
    if (tid < 128) {
        int i = row0 + tid;
        if (i >= ne) i = ne - 1;
        toks[tid] = list[e * CAP + i];
        wts[tid]  = wlist[e * CAP + i];
    }
    __syncthreads();

    const int wave = tid >> 6, lane = tid & 63;
    const int wr = wave >> 1, wc = wave & 1;

    const int c0 = wave, c1 = wave + 4;
    const int lrow = lane >> 2;
    const int lcol = (lane & 3) * 8;
    const int ar0 = c0 * 16 + lrow;
    const int ar1 = c1 * 16 + lrow;
    const unsigned short* a0 = H + (size_t)(hbase + row0 + ar0) * F_DIM + lcol;
    const unsigned short* a1 = H + (size_t)(hbase + row0 + ar1) * F_DIM + lcol;
    const unsigned short* bp = w2b + (size_t)e * D_DIM * F_DIM;
    const unsigned short* b0 = bp + (size_t)(n0 + ar0) * F_DIM + lcol;
    const unsigned short* b1 = bp + (size_t)(n0 + ar1) * F_DIM + lcol;

    unsigned short* Ad0 = &As[c0 * 512];
    unsigned short* Ad1 = &As[c1 * 512];
    unsigned short* Bd0 = &Bs[c0 * 512];
    unsigned short* Bd1 = &Bs[c1 * 512];

    f32x4 acc[4][4];
    #pragma unroll
    for (int m = 0; m < 4; ++m)
        #pragma unroll
        for (int n = 0; n < 4; ++n) acc[m][n] = (f32x4){0.f, 0.f, 0.f, 0.f};

    const int arow = lane & 15;
    const int kg = (lane >> 4) * 8;

    for (int k0 = 0; k0 < F_DIM; k0 += 32) {
        async_copy16(Ad0, a0 + k0);
        async_copy16(Ad1, a1 + k0);
        async_copy16(Bd0, b0 + k0);
        async_copy16(Bd1, b1 + k0);
        __syncthreads();
        bf16x8 af[4], bfr[4];
        #pragma unroll
        for (int m = 0; m < 4; ++m)
            af[m] = *(const bf16x8*)&As[(wr * 64 + m * 16 + arow) * 32 + kg];
        #pragma unroll
        for (int n = 0; n < 4; ++n)
            bfr[n] = *(const bf16x8*)&Bs[(wc * 64 + n * 16 + arow) * 32 + kg];
        #pragma unroll
        for (int m = 0; m < 4; ++m)
            #pragma unroll
            for (int n = 0; n < 4; ++n)
                acc[m][n] = __builtin_amdgcn_mfma_f32_16x16x32_bf16(af[m], bfr[n], acc[m][n], 0, 0, 0);
        __syncthreads();
    }

    #pragma unroll
    for (int m = 0; m < 4; ++m) {
        #pragma unroll
        for (int j = 0; j < 4; ++j) {
            int ri = wr * 64 + m * 16 + (lane >> 4) * 4 + j;
            int i = row0 + ri;
            if (i < ne) {
                int t = toks[ri];
                float wt = wts[ri];
                float* op = out + (size_t)t * D_DIM + n0 + wc * 64;
                #pragma unroll
                for (int n = 0; n < 4; ++n)
                    atomicAdd(&op[n * 16 + (lane & 15)], wt * acc[m][n][j]);
            }
        }
    }
}

extern "C" void kernel_launch(void* const* d_in, const int* in_sizes, int n_in,
                              void* d_out, int out_size, void* d_ws, size_t ws_size,
                              hipStream_t stream)
{
    const float* x    = (const float*)d_in[0];
    const float* bias = (const float*)d_in[1];
    const float* rw   = (const float*)d_in[2];
    const float* w1   = (const float*)d_in[3];
    const float* w2   = (const float*)d_in[4];
    float* out = (float*)d_out;

    char* ws = (char*)d_ws;
    size_t cur = 0;
    auto alloc = [&](size_t bytes) -> void* {
        void* p = (void*)(ws + cur);
        cur += (bytes + 255) & ~(size_t)255;
        return p;
    };
    unsigned short* xb   = (unsigned short*)alloc((size_t)NTOK * D_DIM * 2);
    unsigned short* w1b  = (unsigned short*)alloc((size_t)NEXP * F_DIM * D_DIM * 2);
    unsigned short* w2b  = (unsigned short*)alloc((size_t)NEXP * F_DIM * D_DIM * 2);
    unsigned short* Hb   = (unsigned short*)alloc((size_t)(NTOK * 2 + 128) * F_DIM * 2);
    float* logits = (float*)alloc((size_t)NTOK * NEXP * 4);
    int*   list   = (int*)alloc(NEXP * CAP * 4);
    float* wlist  = (float*)alloc(NEXP * CAP * 4);
    int*   counts = (int*)alloc(64);
    int*   offs   = (int*)alloc(64);

    hipMemsetAsync(counts, 0, 64, stream);
    hipMemsetAsync(out, 0, (size_t)out_size * 4, stream);

    cvt_kernel<<<NTOK * D_DIM / 2048, 256, 0, stream>>>(x, xb, NTOK * D_DIM);
    cvt_kernel<<<NEXP * F_DIM * D_DIM / 2048, 256, 0, stream>>>(w1, w1b, NEXP * F_DIM * D_DIM);
    cvt_kernel<<<NEXP * F_DIM * D_DIM / 2048, 256, 0, stream>>>(w2, w2b, NEXP * F_DIM * D_DIM);
    logits_kernel<<<NTOK / 4, 256, 0, stream>>>(x, rw, logits);
    assign_kernel<<<NTOK / 256, 256, 0, stream>>>(logits, bias, counts, list, wlist);
    scan_kernel<<<1, 64, 0, stream>>>(counts, offs);
    gemm1_kernel<<<dim3(8, 256), 256, 0, stream>>>(xb, w1b, counts, offs, list, Hb);
    gemm2_kernel<<<dim3(8, 256), 256, 0, stream>>>(Hb, w2b, counts, offs, list, wlist, out);
}